// Round 1
// baseline (226.825 us; speedup 1.0000x reference)
//
#include <hip/hip_runtime.h>
#include <hip/hip_bf16.h>
#include <math.h>

// Fused FeedForwardQuantum:
//   g[m,q] = cos(x[m,q]) * cos(theta[q])           (q < 4)
//   h      = relu(g @ W1 + b1)                     (never hits HBM)
//   out    = h @ W2 + b2                           (bf16 MFMA, f32 accum)
//
// 128x128 output tile per 256-thread block, BK=64, 4 waves in 2x2,
// each wave 64x64 via 4x4 frags of v_mfma_f32_16x16x32_bf16.
// LDS tiles stored [row][k] with k-octet XOR swizzle (ko ^= row&7) so both
// ds_write_b128 (stage) and ds_read_b128 (frags) are ~2-way conflict max.

typedef __bf16 bf16_t;
typedef __attribute__((ext_vector_type(8))) __bf16 bf16x8;
typedef __attribute__((ext_vector_type(4))) float f32x4;

#define M_TOT 16384
#define E_DIM 768
#define F_DIM 3072

constexpr int BM = 128, BN = 128, BK = 64;
constexpr int MT = M_TOT / BM;   // 128 m-tiles
constexpr int NT = E_DIM / BN;   // 6 n-tiles

__global__ __launch_bounds__(256, 2)
void ffq_fused(const float* __restrict__ x, const float* __restrict__ theta,
               const float* __restrict__ W1, const float* __restrict__ b1,
               const float* __restrict__ W2, const float* __restrict__ b2,
               float* __restrict__ out)
{
    __shared__ bf16_t Asm[BM][BK];   // h tile,  [m][k] swizzled
    __shared__ bf16_t Bsm[BN][BK];   // W2 tile, [n][k] swizzled (transposed)
    __shared__ float  gsm[BM][4];
    __shared__ float  b2sm[BN];

    const int t    = threadIdx.x;
    const int lane = t & 63;
    const int wid  = t >> 6;

    // XCD-aware swizzle: consecutive work on one XCD shares the W2 n-slab.
    const int bid   = blockIdx.x;
    const int swz   = (bid & 7) * (MT * NT / 8) + (bid >> 3);
    const int ntile = swz / MT;      // mtile fastest within a chunk
    const int mtile = swz % MT;
    const int m0 = mtile * BM, n0 = ntile * BN;

    // ---- prologue: per-row g vectors + b2 slice ----
    const float c0 = cosf(theta[0]);
    const float c1 = cosf(theta[1]);
    const float c2 = cosf(theta[2]);
    const float c3 = cosf(theta[3]);
    if (t < BM) {
        const float4 xv = *reinterpret_cast<const float4*>(x + (size_t)(m0 + t) * E_DIM);
        gsm[t][0] = cosf(xv.x) * c0;
        gsm[t][1] = cosf(xv.y) * c1;
        gsm[t][2] = cosf(xv.z) * c2;
        gsm[t][3] = cosf(xv.w) * c3;
    } else {
        const int n = t - 128;       // BN == 128
        b2sm[n] = b2[n0 + n];
    }
    __syncthreads();

    // staging roles
    const int rg = t >> 3;           // 0..31: row group (4 rows) for A-gen
    const int kg = t & 7;            // 0..7 : k-octet for A-gen
    const int nB = t & 127;          // 0..127: n for B-stage
    const int kh = t >> 7;           // 0..1 : k-half for B-stage

    // mfma roles
    const int wr = wid >> 1, wc = wid & 1;
    const int fr = lane & 15;        // fragment row/col
    const int fg = lane >> 4;        // k-octet group

    f32x4 acc[4][4] = {};

    for (int k0 = 0; k0 < F_DIM; k0 += BK) {
        // ---- A-gen: h[m0+row][k0 + kg*8 .. +7] -> Asm ----
        {
            const int kA = k0 + (kg << 3);
            float w1v[4][8], b1v[8];
            #pragma unroll
            for (int q = 0; q < 4; ++q) {
                const float4 lo = *reinterpret_cast<const float4*>(&W1[q * F_DIM + kA]);
                const float4 hi = *reinterpret_cast<const float4*>(&W1[q * F_DIM + kA + 4]);
                w1v[q][0] = lo.x; w1v[q][1] = lo.y; w1v[q][2] = lo.z; w1v[q][3] = lo.w;
                w1v[q][4] = hi.x; w1v[q][5] = hi.y; w1v[q][6] = hi.z; w1v[q][7] = hi.w;
            }
            {
                const float4 lo = *reinterpret_cast<const float4*>(&b1[kA]);
                const float4 hi = *reinterpret_cast<const float4*>(&b1[kA + 4]);
                b1v[0] = lo.x; b1v[1] = lo.y; b1v[2] = lo.z; b1v[3] = lo.w;
                b1v[4] = hi.x; b1v[5] = hi.y; b1v[6] = hi.z; b1v[7] = hi.w;
            }
            #pragma unroll
            for (int r = 0; r < 4; ++r) {
                const int row = (rg << 2) + r;
                const float4 g = *reinterpret_cast<const float4*>(&gsm[row][0]);
                bf16x8 v;
                #pragma unroll
                for (int kk = 0; kk < 8; ++kk) {
                    float p = b1v[kk];
                    p = fmaf(g.x, w1v[0][kk], p);
                    p = fmaf(g.y, w1v[1][kk], p);
                    p = fmaf(g.z, w1v[2][kk], p);
                    p = fmaf(g.w, w1v[3][kk], p);
                    p = fmaxf(p, 0.0f);
                    v[kk] = (bf16_t)p;
                }
                *reinterpret_cast<bf16x8*>(&Asm[row][(kg ^ (row & 7)) << 3]) = v;
            }
        }
        // ---- B-stage: W2[k0+kh*32+kk][n0+nB] -> Bsm[nB][k] (bf16, transposed) ----
        {
            const float* w2p = W2 + (size_t)(k0 + (kh << 5)) * E_DIM + n0 + nB;
            float bv[32];
            #pragma unroll
            for (int kk = 0; kk < 32; ++kk)
                bv[kk] = w2p[kk * E_DIM];
            #pragma unroll
            for (int o = 0; o < 4; ++o) {
                bf16x8 v;
                #pragma unroll
                for (int j = 0; j < 8; ++j)
                    v[j] = (bf16_t)bv[(o << 3) + j];
                *reinterpret_cast<bf16x8*>(&Bsm[nB][(((kh << 2) + o) ^ (nB & 7)) << 3]) = v;
            }
        }
        __syncthreads();

        // ---- MFMA: 2 k-slices of 32, 4x4 fragments per wave ----
        #pragma unroll
        for (int ks = 0; ks < 2; ++ks) {
            const int kob = (ks << 2) + fg;   // logical k-octet
            bf16x8 af[4], bfr[4];
            #pragma unroll
            for (int mi = 0; mi < 4; ++mi) {
                const int row = (wr << 6) + (mi << 4) + fr;
                af[mi] = *reinterpret_cast<const bf16x8*>(&Asm[row][(kob ^ (row & 7)) << 3]);
            }
            #pragma unroll
            for (int ni = 0; ni < 4; ++ni) {
                const int rn = (wc << 6) + (ni << 4) + fr;
                bfr[ni] = *reinterpret_cast<const bf16x8*>(&Bsm[rn][(kob ^ (rn & 7)) << 3]);
            }
            #pragma unroll
            for (int mi = 0; mi < 4; ++mi) {
                #pragma unroll
                for (int ni = 0; ni < 4; ++ni) {
                    acc[mi][ni] = __builtin_amdgcn_mfma_f32_16x16x32_bf16(
                        af[mi], bfr[ni], acc[mi][ni], 0, 0, 0);
                }
            }
        }
        __syncthreads();
    }

    // ---- epilogue: C = acc + b2  (C/D layout: col=lane&15, row=(lane>>4)*4+r) ----
    #pragma unroll
    for (int mi = 0; mi < 4; ++mi) {
        #pragma unroll
        for (int ni = 0; ni < 4; ++ni) {
            const int col  = n0 + (wc << 6) + (ni << 4) + fr;
            const float bias = b2sm[(wc << 6) + (ni << 4) + fr];
            #pragma unroll
            for (int r = 0; r < 4; ++r) {
                const int row = m0 + (wr << 6) + (mi << 4) + (fg << 2) + r;
                out[(size_t)row * E_DIM + col] = acc[mi][ni][r] + bias;
            }
        }
    }
}

extern "C" void kernel_launch(void* const* d_in, const int* in_sizes, int n_in,
                              void* d_out, int out_size, void* d_ws, size_t ws_size,
                              hipStream_t stream) {
    const float* x     = (const float*)d_in[0];
    const float* theta = (const float*)d_in[1];
    const float* W1    = (const float*)d_in[2];
    const float* b1    = (const float*)d_in[3];
    const float* W2    = (const float*)d_in[4];
    const float* b2    = (const float*)d_in[5];
    float* out = (float*)d_out;

    dim3 grid(MT * NT);   // 768 blocks
    dim3 block(256);
    hipLaunchKernelGGL(ffq_fused, grid, block, 0, stream,
                       x, theta, W1, b1, W2, b2, out);
}